// Round 1
// baseline (106.318 us; speedup 1.0000x reference)
//
#include <hip/hip_runtime.h>
#include <math.h>

// NetVLAD: B=8, N=2048, D=128, K=64, fp32 in/out.
#define BB 8
#define NN 2048
#define DD 128
#define KK 64
#define PP 32            // blocks per batch for K1
#define NPB (NN / PP)    // 64 descriptors per block

// ---------------------------------------------------------------------------
// K1: fused normalize + assignment softmax + weighted accumulation.
// Grid: BB*PP blocks of 256 threads. Each block handles 64 descriptors of one
// batch and emits a partial vlad accumulator [64][128] plus partial sumA[64].
//
// Thread mapping: t = kq*8 + pr.  kq in [0,32) owns k = {2kq, 2kq+1};
// pr in [0,8) owns d-range [pr*16, pr*16+16) as 4 float4 chunks, read in a
// pr-rotated order so the 8 parts hit distinct bank groups (max 2-way = free).
// Centroid fragments (32 floats) and accumulators (32 floats) live in
// registers; only xn (8x128), exp values (8x64) and 8 reciprocal sums touch
// LDS.
// ---------------------------------------------------------------------------
__global__ __launch_bounds__(256) void netvlad_k1(
    const float* __restrict__ x, const float* __restrict__ cent,
    float* __restrict__ part_acc, float* __restrict__ part_sA)
{
    const int b    = blockIdx.x >> 5;   // / PP
    const int p    = blockIdx.x & 31;   // % PP
    const int t    = threadIdx.x;
    const int kq   = t >> 3;            // 0..31
    const int pr   = t & 7;             // 0..7
    const int dbase = pr * 16;
    const int wave = t >> 6;
    const int lane = t & 63;
    const int half = (t >> 5) & 1;
    const int hl   = t & 31;

    __shared__ float xn[8][DD];     // 4 KB: normalized descriptors for this iter
    __shared__ float eL[8][KK];     // 2 KB: exp(dist') values
    __shared__ float rsum[8];       // reciprocal softmax denominators

    // Rotated chunk offsets: register slot jj maps to physical d-chunk
    // ((jj+pr)&3) inside this thread's 16-float range. Static indexing only.
    int off[4];
    #pragma unroll
    for (int jj = 0; jj < 4; ++jj) off[jj] = dbase + (((jj + pr) & 3) << 2);

    // Load centroid fragments into registers + compute ||c_k||^2.
    float4 cA[4], cB[4];
    float cn2a = 0.f, cn2b = 0.f;
    #pragma unroll
    for (int jj = 0; jj < 4; ++jj) {
        cA[jj] = *(const float4*)(cent + (2 * kq) * DD + off[jj]);
        cB[jj] = *(const float4*)(cent + (2 * kq + 1) * DD + off[jj]);
        cn2a += cA[jj].x*cA[jj].x + cA[jj].y*cA[jj].y + cA[jj].z*cA[jj].z + cA[jj].w*cA[jj].w;
        cn2b += cB[jj].x*cB[jj].x + cB[jj].y*cB[jj].y + cB[jj].z*cB[jj].z + cB[jj].w*cB[jj].w;
    }
    #pragma unroll
    for (int m = 1; m < 8; m <<= 1) {
        cn2a += __shfl_xor(cn2a, m);
        cn2b += __shfl_xor(cn2b, m);
    }

    float4 acc0[4], acc1[4];
    #pragma unroll
    for (int jj = 0; jj < 4; ++jj) {
        acc0[jj] = make_float4(0.f, 0.f, 0.f, 0.f);
        acc1[jj] = make_float4(0.f, 0.f, 0.f, 0.f);
    }
    float sA0 = 0.f, sA1 = 0.f;

    const float* xb = x + ((size_t)b * NN + (size_t)p * NPB) * DD;

    for (int it = 0; it < NPB / 8; ++it) {
        __syncthreads();  // protect xn/eL against previous-iteration readers

        // ---- Phase A: load + L2-normalize 8 descriptors (one per half-wave)
        {
            const int i = wave * 2 + half;
            const float* xp = xb + (size_t)(it * 8 + i) * DD + hl * 4;
            float4 v = *(const float4*)xp;
            float ss = v.x*v.x + v.y*v.y + v.z*v.z + v.w*v.w;
            #pragma unroll
            for (int m = 1; m < 32; m <<= 1) ss += __shfl_xor(ss, m);
            const float rn = 1.0f / fmaxf(sqrtf(ss), 1e-12f);
            *(float4*)(&xn[i][hl * 4]) = make_float4(v.x*rn, v.y*rn, v.z*rn, v.w*rn);
        }
        __syncthreads();

        // ---- Phase B: dot products + exp.  assign ∝ exp(||c||^2 - 2 xn·c)
        float e0[8], e1[8];
        #pragma unroll
        for (int i = 0; i < 8; ++i) {
            float S0 = 0.f, S1 = 0.f;
            #pragma unroll
            for (int jj = 0; jj < 4; ++jj) {
                float4 v = *(const float4*)(&xn[i][off[jj]]);
                S0 += v.x*cA[jj].x + v.y*cA[jj].y + v.z*cA[jj].z + v.w*cA[jj].w;
                S1 += v.x*cB[jj].x + v.y*cB[jj].y + v.z*cB[jj].z + v.w*cB[jj].w;
            }
            #pragma unroll
            for (int m = 1; m < 8; m <<= 1) {  // reduce across the 8 d-parts
                S0 += __shfl_xor(S0, m);
                S1 += __shfl_xor(S1, m);
            }
            e0[i] = __expf(cn2a - 2.f * S0);
            e1[i] = __expf(cn2b - 2.f * S1);
            if (pr == 0) *(float2*)(&eL[i][2 * kq]) = make_float2(e0[i], e1[i]);
        }
        __syncthreads();

        // ---- softmax denominators: wave w reduces descriptors 2w, 2w+1
        #pragma unroll
        for (int rep = 0; rep < 2; ++rep) {
            const int i = wave * 2 + rep;
            float e = eL[i][lane];
            #pragma unroll
            for (int m = 1; m < 64; m <<= 1) e += __shfl_xor(e, m);
            if (lane == 0) rsum[i] = 1.0f / e;
        }
        __syncthreads();

        // ---- Phase C: accumulate assign * xn into register tile
        #pragma unroll
        for (int i = 0; i < 8; ++i) {
            const float r = rsum[i];
            const float a0 = e0[i] * r, a1 = e1[i] * r;
            sA0 += a0; sA1 += a1;
            #pragma unroll
            for (int jj = 0; jj < 4; ++jj) {
                float4 v = *(const float4*)(&xn[i][off[jj]]);
                acc0[jj].x += a0*v.x; acc0[jj].y += a0*v.y; acc0[jj].z += a0*v.z; acc0[jj].w += a0*v.w;
                acc1[jj].x += a1*v.x; acc1[jj].y += a1*v.y; acc1[jj].z += a1*v.z; acc1[jj].w += a1*v.w;
            }
        }
    }

    // ---- epilogue: write partial accumulators
    const size_t base = (size_t)(b * PP + p) * KK * DD;
    #pragma unroll
    for (int jj = 0; jj < 4; ++jj) {
        *(float4*)(part_acc + base + (2 * kq) * DD + off[jj])     = acc0[jj];
        *(float4*)(part_acc + base + (2 * kq + 1) * DD + off[jj]) = acc1[jj];
    }
    if (pr == 0) {
        part_sA[(b * PP + p) * KK + 2 * kq]     = sA0;
        part_sA[(b * PP + p) * KK + 2 * kq + 1] = sA1;
    }
}

// ---------------------------------------------------------------------------
// K2: reduce partials, subtract c*sumA, intra-normalize per (b,k) row,
// accumulate global sumsq per batch. Grid: BB*KK blocks of 128 threads.
// ---------------------------------------------------------------------------
__global__ __launch_bounds__(128) void netvlad_k2(
    const float* __restrict__ cent, const float* __restrict__ part_acc,
    const float* __restrict__ part_sA, float* __restrict__ out,
    float* __restrict__ gnorm)
{
    const int b = blockIdx.x >> 6;
    const int k = blockIdx.x & 63;
    const int d = threadIdx.x;   // 0..127

    float sAt = 0.f;
    #pragma unroll
    for (int p = 0; p < PP; ++p) sAt += part_sA[(b * PP + p) * KK + k];

    float v = 0.f;
    #pragma unroll 8
    for (int p = 0; p < PP; ++p)
        v += part_acc[(size_t)(b * PP + p) * KK * DD + k * DD + d];
    v -= cent[k * DD + d] * sAt;

    // intra-normalization: sumsq over the 128-long row (2 waves)
    float ss = v * v;
    #pragma unroll
    for (int m = 1; m < 64; m <<= 1) ss += __shfl_xor(ss, m);
    __shared__ float s2[2];
    if ((d & 63) == 0) s2[d >> 6] = ss;
    __syncthreads();
    const float tot = s2[0] + s2[1];
    const float rn = 1.0f / fmaxf(sqrtf(tot), 1e-12f);
    out[(size_t)b * KK * DD + k * DD + d] = v * rn;

    if (d == 0) atomicAdd(&gnorm[b], tot * rn * rn);  // row sumsq post-norm
}

// ---------------------------------------------------------------------------
// K3: global L2 normalization (in-place on d_out). Grid: 64 blocks of 256.
// ---------------------------------------------------------------------------
__global__ __launch_bounds__(256) void netvlad_k3(
    float* __restrict__ out, const float* __restrict__ gnorm)
{
    const int b = blockIdx.x >> 3;
    const int chunk = blockIdx.x & 7;
    const float rs = 1.0f / fmaxf(sqrtf(gnorm[b]), 1e-12f);
    float4* p = (float4*)(out + (size_t)b * KK * DD) + chunk * 256 + threadIdx.x;
    float4 v = *p;
    v.x *= rs; v.y *= rs; v.z *= rs; v.w *= rs;
    *p = v;
}

extern "C" void kernel_launch(void* const* d_in, const int* in_sizes, int n_in,
                              void* d_out, int out_size, void* d_ws, size_t ws_size,
                              hipStream_t stream) {
    const float* x    = (const float*)d_in[0];   // [8, 2048, 128] fp32
    const float* cent = (const float*)d_in[1];   // [64, 128] fp32
    float* out = (float*)d_out;                  // [8, 8192] fp32

    char* ws = (char*)d_ws;
    float* gnorm    = (float*)ws;                        // 32 B
    float* part_sA  = (float*)(ws + 4096);               // 8*32*64 fp32 = 64 KB
    float* part_acc = (float*)(ws + 4096 + 65536);       // 8*32*64*128 fp32 = 8 MB

    hipMemsetAsync(gnorm, 0, BB * sizeof(float), stream);

    netvlad_k1<<<dim3(BB * PP), dim3(256), 0, stream>>>(x, cent, part_acc, part_sA);
    netvlad_k2<<<dim3(BB * KK), dim3(128), 0, stream>>>(cent, part_acc, part_sA, out, gnorm);
    netvlad_k3<<<dim3(64), dim3(256), 0, stream>>>(out, gnorm);
}

// Round 2
// 98.872 us; speedup vs baseline: 1.0753x; 1.0753x over previous
//
#include <hip/hip_runtime.h>
#include <math.h>

// NetVLAD: B=8, N=2048, D=128, K=64, fp32 in/out.
#define BB 8
#define NN 2048
#define DD 128
#define KK 64
#define PP 128           // blocks per batch for K1 (1024 blocks = 4/CU)
#define NPB (NN / PP)    // 16 descriptors per block

// ---------------------------------------------------------------------------
// K1: fused normalize + assignment softmax + weighted accumulation.
// Grid: BB*PP = 1024 blocks of 256 threads (4 blocks/CU, 16 waves/CU).
// Each block handles 16 descriptors of one batch and emits a partial vlad
// accumulator [64][128] plus partial sumA[64].
//
// Thread mapping: t = kq*8 + pr.  kq in [0,32) owns k = {2kq, 2kq+1};
// pr in [0,8) owns d-range [pr*16, pr*16+16) as 4 float4 chunks, read in a
// pr-rotated order so bank aliasing is at most 2-way (free on gfx950).
// Centroid fragments (32 floats) and accumulators (32 floats) live in
// registers; only xn (8x128), exp values (8x64) and 8 reciprocal sums touch
// LDS.
// ---------------------------------------------------------------------------
__global__ __launch_bounds__(256, 4) void netvlad_k1(
    const float* __restrict__ x, const float* __restrict__ cent,
    float* __restrict__ part_acc, float* __restrict__ part_sA)
{
    const int b    = blockIdx.x >> 7;    // / PP
    const int p    = blockIdx.x & 127;   // % PP
    const int t    = threadIdx.x;
    const int kq   = t >> 3;             // 0..31
    const int pr   = t & 7;              // 0..7
    const int dbase = pr * 16;
    const int wave = t >> 6;
    const int lane = t & 63;
    const int half = (t >> 5) & 1;
    const int hl   = t & 31;

    __shared__ float xn[8][DD];     // 4 KB: normalized descriptors for this iter
    __shared__ float eL[8][KK];     // 2 KB: exp(dist') values
    __shared__ float rsum[8];       // reciprocal softmax denominators

    // Rotated chunk offsets: register slot jj maps to physical d-chunk
    // ((jj+pr)&3) inside this thread's 16-float range. Static indexing only.
    int off[4];
    #pragma unroll
    for (int jj = 0; jj < 4; ++jj) off[jj] = dbase + (((jj + pr) & 3) << 2);

    // Load centroid fragments into registers + compute ||c_k||^2.
    float4 cA[4], cB[4];
    float cn2a = 0.f, cn2b = 0.f;
    #pragma unroll
    for (int jj = 0; jj < 4; ++jj) {
        cA[jj] = *(const float4*)(cent + (2 * kq) * DD + off[jj]);
        cB[jj] = *(const float4*)(cent + (2 * kq + 1) * DD + off[jj]);
        cn2a += cA[jj].x*cA[jj].x + cA[jj].y*cA[jj].y + cA[jj].z*cA[jj].z + cA[jj].w*cA[jj].w;
        cn2b += cB[jj].x*cB[jj].x + cB[jj].y*cB[jj].y + cB[jj].z*cB[jj].z + cB[jj].w*cB[jj].w;
    }
    #pragma unroll
    for (int m = 1; m < 8; m <<= 1) {
        cn2a += __shfl_xor(cn2a, m);
        cn2b += __shfl_xor(cn2b, m);
    }

    float4 acc0[4], acc1[4];
    #pragma unroll
    for (int jj = 0; jj < 4; ++jj) {
        acc0[jj] = make_float4(0.f, 0.f, 0.f, 0.f);
        acc1[jj] = make_float4(0.f, 0.f, 0.f, 0.f);
    }
    float sA0 = 0.f, sA1 = 0.f;

    const float* xb = x + ((size_t)b * NN + (size_t)p * NPB) * DD;

    for (int it = 0; it < NPB / 8; ++it) {
        __syncthreads();  // protect xn/eL against previous-iteration readers

        // ---- Phase A: load + L2-normalize 8 descriptors (one per half-wave)
        {
            const int i = wave * 2 + half;
            const float* xp = xb + (size_t)(it * 8 + i) * DD + hl * 4;
            float4 v = *(const float4*)xp;
            float ss = v.x*v.x + v.y*v.y + v.z*v.z + v.w*v.w;
            #pragma unroll
            for (int m = 1; m < 32; m <<= 1) ss += __shfl_xor(ss, m);
            const float rn = 1.0f / fmaxf(sqrtf(ss), 1e-12f);
            *(float4*)(&xn[i][hl * 4]) = make_float4(v.x*rn, v.y*rn, v.z*rn, v.w*rn);
        }
        __syncthreads();

        // ---- Phase B: dot products + exp.  assign ∝ exp(||c||^2 - 2 xn·c)
        float e0[8], e1[8];
        #pragma unroll
        for (int i = 0; i < 8; ++i) {
            float S0 = 0.f, S1 = 0.f;
            #pragma unroll
            for (int jj = 0; jj < 4; ++jj) {
                float4 v = *(const float4*)(&xn[i][off[jj]]);
                S0 += v.x*cA[jj].x + v.y*cA[jj].y + v.z*cA[jj].z + v.w*cA[jj].w;
                S1 += v.x*cB[jj].x + v.y*cB[jj].y + v.z*cB[jj].z + v.w*cB[jj].w;
            }
            #pragma unroll
            for (int m = 1; m < 8; m <<= 1) {  // reduce across the 8 d-parts
                S0 += __shfl_xor(S0, m);
                S1 += __shfl_xor(S1, m);
            }
            e0[i] = __expf(cn2a - 2.f * S0);
            e1[i] = __expf(cn2b - 2.f * S1);
            if (pr == 0) *(float2*)(&eL[i][2 * kq]) = make_float2(e0[i], e1[i]);
        }
        __syncthreads();

        // ---- softmax denominators: wave w reduces descriptors 2w, 2w+1
        #pragma unroll
        for (int rep = 0; rep < 2; ++rep) {
            const int i = wave * 2 + rep;
            float e = eL[i][lane];
            #pragma unroll
            for (int m = 1; m < 64; m <<= 1) e += __shfl_xor(e, m);
            if (lane == 0) rsum[i] = 1.0f / e;
        }
        __syncthreads();

        // ---- Phase C: accumulate assign * xn into register tile
        #pragma unroll
        for (int i = 0; i < 8; ++i) {
            const float r = rsum[i];
            const float a0 = e0[i] * r, a1 = e1[i] * r;
            sA0 += a0; sA1 += a1;
            #pragma unroll
            for (int jj = 0; jj < 4; ++jj) {
                float4 v = *(const float4*)(&xn[i][off[jj]]);
                acc0[jj].x += a0*v.x; acc0[jj].y += a0*v.y; acc0[jj].z += a0*v.z; acc0[jj].w += a0*v.w;
                acc1[jj].x += a1*v.x; acc1[jj].y += a1*v.y; acc1[jj].z += a1*v.z; acc1[jj].w += a1*v.w;
            }
        }
    }

    // ---- epilogue: write partial accumulators
    const size_t base = (size_t)(b * PP + p) * KK * DD;
    #pragma unroll
    for (int jj = 0; jj < 4; ++jj) {
        *(float4*)(part_acc + base + (2 * kq) * DD + off[jj])     = acc0[jj];
        *(float4*)(part_acc + base + (2 * kq + 1) * DD + off[jj]) = acc1[jj];
    }
    if (pr == 0) {
        part_sA[(b * PP + p) * KK + 2 * kq]     = sA0;
        part_sA[(b * PP + p) * KK + 2 * kq + 1] = sA1;
    }
}

// ---------------------------------------------------------------------------
// K2: reduce 128 partials per (b,k), subtract c*sumA, intra-normalize, and
// apply the global L2 factor. Since every intra-normalized row has sumsq == 1
// (to ~1e-7), the global norm is exactly sqrt(K)=8 — fold 0.125 here and skip
// the separate gnorm/K3 pass entirely (error ~1e-8 vs 5.5e-4 threshold).
// Grid: BB*KK = 512 blocks of 128 threads.
// Thread t: d4 = t&31 (float4 column), ps = t>>5 (p-slice of 32).
// ---------------------------------------------------------------------------
__global__ __launch_bounds__(128) void netvlad_k2(
    const float* __restrict__ cent, const float* __restrict__ part_acc,
    const float* __restrict__ part_sA, float* __restrict__ out)
{
    const int b  = blockIdx.x >> 6;
    const int k  = blockIdx.x & 63;
    const int t  = threadIdx.x;
    const int d4 = t & 31;
    const int ps = t >> 5;

    // ---- sumA: 128 threads, one partial each, block-reduce
    __shared__ float sAL[2];
    {
        float sA = part_sA[(b * PP + t) * KK + k];
        #pragma unroll
        for (int m = 1; m < 64; m <<= 1) sA += __shfl_xor(sA, m);
        if ((t & 63) == 0) sAL[t >> 6] = sA;
    }

    // ---- vlad partial sum: each thread sums 32 p's for its float4 column
    float4 acc = make_float4(0.f, 0.f, 0.f, 0.f);
    const float* base = part_acc + ((size_t)(b * PP) * KK + k) * DD + d4 * 4;
    #pragma unroll 8
    for (int pp = 0; pp < 32; ++pp) {
        const float4 v = *(const float4*)(base + (size_t)(ps * 32 + pp) * KK * DD);
        acc.x += v.x; acc.y += v.y; acc.z += v.z; acc.w += v.w;
    }

    __shared__ float4 red[4][32];
    red[ps][d4] = acc;
    __syncthreads();
    const float sAt = sAL[0] + sAL[1];

    if (t < 32) {
        float4 v = red[0][t];
        #pragma unroll
        for (int s = 1; s < 4; ++s) {
            v.x += red[s][t].x; v.y += red[s][t].y;
            v.z += red[s][t].z; v.w += red[s][t].w;
        }
        const float4 c = *(const float4*)(cent + k * DD + t * 4);
        v.x -= c.x * sAt; v.y -= c.y * sAt; v.z -= c.z * sAt; v.w -= c.w * sAt;

        float ss = v.x*v.x + v.y*v.y + v.z*v.z + v.w*v.w;
        #pragma unroll
        for (int m = 1; m < 32; m <<= 1) ss += __shfl_xor(ss, m);
        const float rn = 0.125f / fmaxf(sqrtf(ss), 1e-12f);
        v.x *= rn; v.y *= rn; v.z *= rn; v.w *= rn;
        *(float4*)(out + ((size_t)b * KK + k) * DD + t * 4) = v;
    }
}

extern "C" void kernel_launch(void* const* d_in, const int* in_sizes, int n_in,
                              void* d_out, int out_size, void* d_ws, size_t ws_size,
                              hipStream_t stream) {
    const float* x    = (const float*)d_in[0];   // [8, 2048, 128] fp32
    const float* cent = (const float*)d_in[1];   // [64, 128] fp32
    float* out = (float*)d_out;                  // [8, 8192] fp32

    char* ws = (char*)d_ws;
    float* part_sA  = (float*)ws;                 // 8*128*64 fp32 = 256 KB
    float* part_acc = (float*)(ws + (1 << 19));   // 8*128*64*128 fp32 = 32 MB

    netvlad_k1<<<dim3(BB * PP), dim3(256), 0, stream>>>(x, cent, part_acc, part_sA);
    netvlad_k2<<<dim3(BB * KK), dim3(128), 0, stream>>>(cent, part_acc, part_sA, out);
}